// Round 13
// baseline (211.990 us; speedup 1.0000x reference)
//
#include <hip/hip_runtime.h>
#include <hip/hip_bf16.h>

#define BATCH 16
#define HW 50176          // 224*224
#define HID 256
#define K 64

// output layout (floats): transformed [0, 2408448) | m [2408448, 53788672) | palette [53788672, +3072)
#define OUT_T_OFF 0
#define OUT_M_OFF 2408448
#define OUT_P_OFF 53788672

// workspace layout (floats): den [0,1024) | num [1024,4096) | w1p float4 [4096,5120) | w2b bf16 @ float-offset 5120 (32KB)
#define WS_DEN 0
#define WS_NUM 1024
#define WS_W1P 4096
#define WS_W2B 5120

typedef short bf16x8 __attribute__((ext_vector_type(8)));
typedef float f32x4  __attribute__((ext_vector_type(4)));

static __device__ __forceinline__ short f2bf(float x) {
    union { __hip_bfloat16 h; short s; } u;
    u.h = __float2bfloat16(x);
    return u.s;
}

// Prep (8 blocks): block 0 zeroes den/num and packs W1+b1 (linear); all blocks convert W2 to bf16.
__global__ __launch_bounds__(256) void colorcnn_prep(
    const float* __restrict__ W1, const float* __restrict__ b1,
    const float* __restrict__ W2, float* __restrict__ wsf,
    float4* __restrict__ w1p, ushort* __restrict__ w2b)
{
    const int t = threadIdx.x;
    if (blockIdx.x == 0) {
#pragma unroll
        for (int q = 0; q < 16; ++q) wsf[q * 256 + t] = 0.f;   // den[1024] + num[3072]
        w1p[t] = make_float4(W1[3 * t], W1[3 * t + 1], W1[3 * t + 2], b1[t]);
    }
#pragma unroll
    for (int q = 0; q < 8; ++q) {
        const int i = (blockIdx.x * 8 + q) * 256 + t;
        w2b[i] = (ushort)f2bf(W2[i]);
    }
}

// Kernel A: MLP via MFMA + softmax + fused den/num reduction + m store last.
// (v10 form, measured 124.99 total; launched TWICE this round to measure A directly —
//  safe because palette=num/(den+eps) is scale-invariant under doubling of num & den.)
__global__ __launch_bounds__(256, 4) void colorcnn_mlp_softmax(
    const float* __restrict__ img, const float4* __restrict__ w1p,
    const ushort* __restrict__ w2b, float* __restrict__ m_out,
    float* __restrict__ den_ws, float* __restrict__ num_ws)
{
    __shared__ int4 lds[2304];       // [0,2048): w2b swizzled; [2048,2304): w1p linear
    __shared__ float sred[4][256];   // per-wave den/num partials

    const int t = threadIdx.x;
    const int4* w2b16 = (const int4*)w2b;
#pragma unroll
    for (int q = 0; q < 8; ++q) {
        const int i = t + q * 256;
        const int n = i >> 5, s = i & 31;
        lds[n * 32 + (s ^ (n & 7))] = w2b16[i];
    }
    lds[2048 + t] = ((const int4*)w1p)[t];
    __syncthreads();

    const int b    = blockIdx.y;
    const int pb   = blockIdx.x * 128;
    const int w    = t >> 6;
    const int lane = t & 63;
    const int l15  = lane & 15;
    const int lg   = lane >> 4;
    const int pwb  = pb + w * 32;
    const int x7   = l15 & 7;

    const float* ip = img + (size_t)b * 3 * HW;

    float rr[2], gg[2], uu[2];
#pragma unroll
    for (int s = 0; s < 2; ++s) {
        const int px = pwb + s * 16 + l15;
        rr[s] = ip[px]; gg[s] = ip[HW + px]; uu[s] = ip[2 * HW + px];
    }

    f32x4 acc[2][4];
#pragma unroll
    for (int s = 0; s < 2; ++s)
#pragma unroll
        for (int ni = 0; ni < 4; ++ni)
            acc[s][ni] = (f32x4){0.f, 0.f, 0.f, 0.f};

    const float4* w1l = (const float4*)&lds[2048 + lg * 8];

#pragma unroll
    for (int c = 0; c < 8; ++c) {
        union { bf16x8 v; unsigned int u[4]; } ua0, ua1;
#pragma unroll
        for (int p = 0; p < 4; ++p) {          // j = 2p, 2p+1
            const float4 wv0 = w1l[c * 32 + 2 * p];
            const float4 wv1 = w1l[c * 32 + 2 * p + 1];
            const float e0 = fmaxf(fmaf(rr[0], wv0.x, fmaf(gg[0], wv0.y, fmaf(uu[0], wv0.z, wv0.w))), 0.f);
            const float o0 = fmaxf(fmaf(rr[0], wv1.x, fmaf(gg[0], wv1.y, fmaf(uu[0], wv1.z, wv1.w))), 0.f);
            const float e1 = fmaxf(fmaf(rr[1], wv0.x, fmaf(gg[1], wv0.y, fmaf(uu[1], wv0.z, wv0.w))), 0.f);
            const float o1 = fmaxf(fmaf(rr[1], wv1.x, fmaf(gg[1], wv1.y, fmaf(uu[1], wv1.z, wv1.w))), 0.f);
            __hip_bfloat162 c0 = __float22bfloat162_rn(float2{e0, o0});
            __hip_bfloat162 c1 = __float22bfloat162_rn(float2{e1, o1});
            ua0.u[p] = *(unsigned int*)&c0;
            ua1.u[p] = *(unsigned int*)&c1;
        }
        const int sw = (c * 4 + lg) ^ x7;
#pragma unroll
        for (int ni = 0; ni < 4; ++ni) {
            const bf16x8 bf = *(const bf16x8*)&lds[(ni * 16 + l15) * 32 + sw];
            acc[0][ni] = __builtin_amdgcn_mfma_f32_16x16x32_bf16(ua0.v, bf, acc[0][ni], 0, 0, 0);
            acc[1][ni] = __builtin_amdgcn_mfma_f32_16x16x32_bf16(ua1.v, bf, acc[1][ni], 0, 0, 0);
        }
    }

    // Softmax over n=64 per pixel (no max-subtract; logits bounded, fp32 exp safe).
#pragma unroll
    for (int s = 0; s < 2; ++s) {
#pragma unroll
        for (int reg = 0; reg < 4; ++reg) {
            const float v0 = __expf(acc[s][0][reg]);
            const float v1 = __expf(acc[s][1][reg]);
            const float v2 = __expf(acc[s][2][reg]);
            const float v3 = __expf(acc[s][3][reg]);
            float sm = (v0 + v1) + (v2 + v3);
            sm += __shfl_xor(sm, 1);
            sm += __shfl_xor(sm, 2);
            sm += __shfl_xor(sm, 4);
            sm += __shfl_xor(sm, 8);
            const float inv = __builtin_amdgcn_rcpf(sm);
            acc[s][0][reg] = v0 * inv; acc[s][1][reg] = v1 * inv;
            acc[s][2][reg] = v2 * inv; acc[s][3][reg] = v3 * inv;
        }
    }

    // ---- Fused den/num reduction (before global stores; barrier stays cheap) ----
    float red[16];
#pragma unroll
    for (int i = 0; i < 16; ++i) red[i] = 0.f;
#pragma unroll
    for (int s = 0; s < 2; ++s) {
        const int pxb = pwb + s * 16 + lg * 4;
        const f32x4 rC = *(const f32x4*)&ip[pxb];
        const f32x4 gC = *(const f32x4*)&ip[HW + pxb];
        const f32x4 uC = *(const f32x4*)&ip[2 * HW + pxb];
#pragma unroll
        for (int ni = 0; ni < 4; ++ni) {
#pragma unroll
            for (int reg = 0; reg < 4; ++reg) {
                const float mv = acc[s][ni][reg];
                red[ni]      += mv;
                red[4 + ni]   = fmaf(rC[reg], mv, red[4 + ni]);
                red[8 + ni]   = fmaf(gC[reg], mv, red[8 + ni]);
                red[12 + ni]  = fmaf(uC[reg], mv, red[12 + ni]);
            }
        }
    }
#pragma unroll
    for (int i = 0; i < 16; ++i) {
        red[i] += __shfl_xor(red[i], 16);
        red[i] += __shfl_xor(red[i], 32);
    }
    if (lg == 0) {
#pragma unroll
        for (int ni = 0; ni < 4; ++ni) {
            const int n = ni * 16 + l15;
            sred[w][n]       = red[ni];
            sred[w][64 + n]  = red[4 + ni];
            sred[w][128 + n] = red[8 + ni];
            sred[w][192 + n] = red[12 + ni];
        }
    }
    __syncthreads();
    {
        const int q = t >> 6, n = t & 63;
        const float v = sred[0][t] + sred[1][t] + sred[2][t] + sred[3][t];
        if (q == 0) atomicAdd(&den_ws[b * K + n], v);
        else        atomicAdd(&num_ws[(b * 3 + (q - 1)) * K + n], v);
    }

    // Store m LAST: per (s,ni) the 4 regs are 4 consecutive px -> dwordx4.
    float* mo = m_out + (size_t)b * K * HW + pwb;
#pragma unroll
    for (int s = 0; s < 2; ++s)
#pragma unroll
        for (int ni = 0; ni < 4; ++ni) {
            const int n = ni * 16 + l15;
            *(f32x4*)&mo[(size_t)n * HW + s * 16 + lg * 4] = acc[s][ni];
        }
}

// Kernel C: palette (fused) + transformed = sum_k m * palette. 4 px/thread, f32x4.
// (v7 version verbatim — best measured config.)
__global__ __launch_bounds__(256) void colorcnn_reconstruct(
    const float* __restrict__ m, const float* __restrict__ den_ws,
    const float* __restrict__ num_ws, float* __restrict__ pal_out,
    float* __restrict__ t_out)
{
    __shared__ float pl[192];
    const int b    = blockIdx.x / 49;
    const int tile = blockIdx.x % 49;
    const int t    = threadIdx.x;

    if (t < 192) {
        const int c = t >> 6, k = t & 63;
        const float v = num_ws[(b * 3 + c) * K + k] / (den_ws[b * K + k] + 1e-8f);
        pl[t] = v;
        if (tile == 0) pal_out[b * 3 * K + t] = v;
    }
    __syncthreads();

    const int p = tile * 1024 + t * 4;
    const float* mp = m + (size_t)b * K * HW + p;
    f32x4 ar = {0.f, 0.f, 0.f, 0.f}, ag = ar, ab = ar;
#pragma unroll
    for (int k = 0; k < K; ++k) {
        const f32x4 mv = *(const f32x4*)&mp[(size_t)k * HW];
        const float pr = pl[k], pg = pl[K + k], pu = pl[2 * K + k];
#pragma unroll
        for (int j = 0; j < 4; ++j) {
            ar[j] = fmaf(mv[j], pr, ar[j]);
            ag[j] = fmaf(mv[j], pg, ag[j]);
            ab[j] = fmaf(mv[j], pu, ab[j]);
        }
    }
    float* to = t_out + (size_t)b * 3 * HW + p;
    *(f32x4*)&to[0]      = ar;
    *(f32x4*)&to[HW]     = ag;
    *(f32x4*)&to[2 * HW] = ab;
}

extern "C" void kernel_launch(void* const* d_in, const int* in_sizes, int n_in,
                              void* d_out, int out_size, void* d_ws, size_t ws_size,
                              hipStream_t stream) {
    const float* img = (const float*)d_in[0];
    const float* W1  = (const float*)d_in[1];
    const float* b1  = (const float*)d_in[2];
    const float* W2  = (const float*)d_in[3];

    float* out   = (float*)d_out;
    float* t_out = out + OUT_T_OFF;
    float* m_out = out + OUT_M_OFF;
    float* p_out = out + OUT_P_OFF;

    float*  wsf    = (float*)d_ws;
    float*  den_ws = wsf + WS_DEN;
    float*  num_ws = wsf + WS_NUM;
    float4* w1p    = (float4*)(wsf + WS_W1P);
    ushort* w2b    = (ushort*)(wsf + WS_W2B);

    colorcnn_prep<<<8, 256, 0, stream>>>(W1, b1, W2, wsf, w1p, w2b);
    // A launched TWICE: second run recomputes m/t-identical results; den/num double,
    // palette is invariant under that doubling. Measures A's true duration:
    // dur_us(this round) - 124.99 = A.
    colorcnn_mlp_softmax<<<dim3(HW / 128, BATCH), 256, 0, stream>>>(img, w1p, w2b, m_out, den_ws, num_ws);
    colorcnn_mlp_softmax<<<dim3(HW / 128, BATCH), 256, 0, stream>>>(img, w1p, w2b, m_out, den_ws, num_ws);
    colorcnn_reconstruct<<<BATCH * 49, 256, 0, stream>>>(m_out, den_ws, num_ws, p_out, t_out);
}

// Round 14
// 176.575 us; speedup vs baseline: 1.2006x; 1.2006x over previous
//
#include <hip/hip_runtime.h>
#include <hip/hip_bf16.h>

#define BATCH 16
#define HW 50176          // 224*224
#define HID 256
#define K 64

// output layout (floats): transformed [0, 2408448) | m [2408448, 53788672) | palette [53788672, +3072)
#define OUT_T_OFF 0
#define OUT_M_OFF 2408448
#define OUT_P_OFF 53788672

// workspace layout (floats): den [0,1024) | num [1024,4096) | w1p float4 [4096,5120) |
// w2b chunk-swizzled bf16 units (2048 int4 = 32KB) @ float-offset 5120
#define WS_DEN 0
#define WS_NUM 1024
#define WS_W1P 4096
#define WS_W2B 5120

typedef short bf16x8 __attribute__((ext_vector_type(8)));
typedef float f32x4  __attribute__((ext_vector_type(4)));

static __device__ __forceinline__ ushort f2bf(float x) {
    union { __hip_bfloat16 h; ushort s; } u;
    u.h = __float2bfloat16(x);
    return u.s;
}

// Prep (8 blocks): block 0 zeroes den/num + packs W1+b1 (linear float4).
// All blocks: write W2 as chunk-swizzled bf16 16B-units.
// Chunk ch (64 hid), row n, sub-unit jj=(cl*4+lg): value = W2[n][ch*64+cl*32+lg*8 .. +7],
// stored at int4 index ch*512 + n*8 + (jj ^ (n&7)).
__global__ __launch_bounds__(256) void colorcnn_prep(
    const float* __restrict__ W1, const float* __restrict__ b1,
    const float* __restrict__ W2, float* __restrict__ wsf,
    float4* __restrict__ w1p, int4* __restrict__ w2b4)
{
    const int t = threadIdx.x;
    if (blockIdx.x == 0) {
#pragma unroll
        for (int q = 0; q < 16; ++q) wsf[q * 256 + t] = 0.f;   // den[1024] + num[3072]
        w1p[t] = make_float4(W1[3 * t], W1[3 * t + 1], W1[3 * t + 2], b1[t]);
    }
    const int g  = blockIdx.x * 256 + t;    // 0..2047
    const int ch = g >> 9;
    const int n  = (g >> 3) & 63;
    const int jj = g & 7;
    const int cl = jj >> 2;
    const int lg = jj & 3;
    const int hid0 = ch * 64 + cl * 32 + lg * 8;
    union { int4 v; ushort u[8]; } un;
#pragma unroll
    for (int e = 0; e < 8; ++e) un.u[e] = f2bf(W2[n * HID + hid0 + e]);
    w2b4[ch * 512 + n * 8 + (jj ^ (n & 7))] = un.v;
}

// Kernel A: MLP via MFMA + softmax + fused den/num reduction + m store last.
// 512 threads = 8 waves x 32 px = 256 px/block. W2 streamed in 4 quarter-chunks (8KB),
// double-buffered in LDS. Total LDS 28KB -> 4 blocks/CU, wave-capped 32 waves/CU (100%).
__global__ __launch_bounds__(512, 8) void colorcnn_mlp_softmax(
    const float* __restrict__ img, const int4* __restrict__ w1p4,
    const int4* __restrict__ w2b4, float* __restrict__ m_out,
    float* __restrict__ den_ws, float* __restrict__ num_ws)
{
    __shared__ int4  wbuf[2][512];   // 16 KB: double-buffered W2 quarter-chunks
    __shared__ int4  w1l[256];       // 4 KB: w1p XOR-swizzled
    __shared__ float sred[8][256];   // 8 KB: per-wave den/num partials

    const int t = threadIdx.x;
    // prologue: stage chunk 0 + w1p
    wbuf[0][t] = w2b4[t];
    if (t < 256) w1l[t ^ ((t >> 3) & 3)] = w1p4[t];
    __syncthreads();

    const int b    = blockIdx.y;
    const int pb   = blockIdx.x * 256;
    const int w    = t >> 6;
    const int lane = t & 63;
    const int l15  = lane & 15;
    const int lg   = lane >> 4;
    const int pwb  = pb + w * 32;
    const int x7   = l15 & 7;

    const float* ip = img + (size_t)b * 3 * HW;

    float rr[2], gg[2], uu[2];
#pragma unroll
    for (int s = 0; s < 2; ++s) {
        const int px = pwb + s * 16 + l15;
        rr[s] = ip[px]; gg[s] = ip[HW + px]; uu[s] = ip[2 * HW + px];
    }

    f32x4 acc[2][4];
#pragma unroll
    for (int s = 0; s < 2; ++s)
#pragma unroll
        for (int ni = 0; ni < 4; ++ni)
            acc[s][ni] = (f32x4){0.f, 0.f, 0.f, 0.f};

#pragma unroll
    for (int ch = 0; ch < 4; ++ch) {
        int4 stg;
        if (ch < 3) stg = w2b4[(ch + 1) * 512 + t];   // issue early; L2-hit, hides under MFMA
#pragma unroll
        for (int cl = 0; cl < 2; ++cl) {
            const int c = ch * 2 + cl;
            union { bf16x8 v; unsigned int u[4]; } ua0, ua1;
#pragma unroll
            for (int p = 0; p < 4; ++p) {          // j = 2p, 2p+1 ; hid = c*32 + lg*8 + j
                const int hid0 = c * 32 + lg * 8 + 2 * p;
                const float4 wv0 = *(const float4*)&w1l[hid0 ^ lg];
                const float4 wv1 = *(const float4*)&w1l[(hid0 + 1) ^ lg];
                const float e0 = fmaxf(fmaf(rr[0], wv0.x, fmaf(gg[0], wv0.y, fmaf(uu[0], wv0.z, wv0.w))), 0.f);
                const float o0 = fmaxf(fmaf(rr[0], wv1.x, fmaf(gg[0], wv1.y, fmaf(uu[0], wv1.z, wv1.w))), 0.f);
                const float e1 = fmaxf(fmaf(rr[1], wv0.x, fmaf(gg[1], wv0.y, fmaf(uu[1], wv0.z, wv0.w))), 0.f);
                const float o1 = fmaxf(fmaf(rr[1], wv1.x, fmaf(gg[1], wv1.y, fmaf(uu[1], wv1.z, wv1.w))), 0.f);
                __hip_bfloat162 c0 = __float22bfloat162_rn(float2{e0, o0});
                __hip_bfloat162 c1 = __float22bfloat162_rn(float2{e1, o1});
                ua0.u[p] = *(unsigned int*)&c0;
                ua1.u[p] = *(unsigned int*)&c1;
            }
            const int sw = (cl * 4 + lg) ^ x7;
#pragma unroll
            for (int ni = 0; ni < 4; ++ni) {
                const bf16x8 bf = *(const bf16x8*)&wbuf[ch & 1][(ni * 16 + l15) * 8 + sw];
                acc[0][ni] = __builtin_amdgcn_mfma_f32_16x16x32_bf16(ua0.v, bf, acc[0][ni], 0, 0, 0);
                acc[1][ni] = __builtin_amdgcn_mfma_f32_16x16x32_bf16(ua1.v, bf, acc[1][ni], 0, 0, 0);
            }
        }
        if (ch < 3) {
            wbuf[(ch + 1) & 1][t] = stg;   // buffer was last read 2 iters ago; barrier-protected
            __syncthreads();
        }
    }

    // Softmax over n=64 per pixel (no max-subtract; logits bounded, fp32 exp safe).
#pragma unroll
    for (int s = 0; s < 2; ++s) {
#pragma unroll
        for (int reg = 0; reg < 4; ++reg) {
            const float v0 = __expf(acc[s][0][reg]);
            const float v1 = __expf(acc[s][1][reg]);
            const float v2 = __expf(acc[s][2][reg]);
            const float v3 = __expf(acc[s][3][reg]);
            float sm = (v0 + v1) + (v2 + v3);
            sm += __shfl_xor(sm, 1);
            sm += __shfl_xor(sm, 2);
            sm += __shfl_xor(sm, 4);
            sm += __shfl_xor(sm, 8);
            const float inv = __builtin_amdgcn_rcpf(sm);
            acc[s][0][reg] = v0 * inv; acc[s][1][reg] = v1 * inv;
            acc[s][2][reg] = v2 * inv; acc[s][3][reg] = v3 * inv;
        }
    }

    // ---- Fused den/num reduction (before global stores; barrier stays cheap) ----
    float red[16];   // [q*4+ni], q: 0=den 1=numR 2=numG 3=numB ; n = ni*16 + l15
#pragma unroll
    for (int i = 0; i < 16; ++i) red[i] = 0.f;
#pragma unroll
    for (int s = 0; s < 2; ++s) {
        const int pxb = pwb + s * 16 + lg * 4;
        const f32x4 rC = *(const f32x4*)&ip[pxb];
        const f32x4 gC = *(const f32x4*)&ip[HW + pxb];
        const f32x4 uC = *(const f32x4*)&ip[2 * HW + pxb];
#pragma unroll
        for (int ni = 0; ni < 4; ++ni) {
#pragma unroll
            for (int reg = 0; reg < 4; ++reg) {
                const float mv = acc[s][ni][reg];
                red[ni]      += mv;
                red[4 + ni]   = fmaf(rC[reg], mv, red[4 + ni]);
                red[8 + ni]   = fmaf(gC[reg], mv, red[8 + ni]);
                red[12 + ni]  = fmaf(uC[reg], mv, red[12 + ni]);
            }
        }
    }
#pragma unroll
    for (int i = 0; i < 16; ++i) {
        red[i] += __shfl_xor(red[i], 16);
        red[i] += __shfl_xor(red[i], 32);
    }
    if (lg == 0) {
#pragma unroll
        for (int ni = 0; ni < 4; ++ni) {
            const int n = ni * 16 + l15;
            sred[w][n]       = red[ni];
            sred[w][64 + n]  = red[4 + ni];
            sred[w][128 + n] = red[8 + ni];
            sred[w][192 + n] = red[12 + ni];
        }
    }
    __syncthreads();
    if (t < 256) {
        const int q = t >> 6, n = t & 63;
        float v = sred[0][t];
#pragma unroll
        for (int wv = 1; wv < 8; ++wv) v += sred[wv][t];
        if (q == 0) atomicAdd(&den_ws[b * K + n], v);
        else        atomicAdd(&num_ws[(b * 3 + (q - 1)) * K + n], v);
    }

    // Store m LAST: per (s,ni) the 4 regs are 4 consecutive px -> dwordx4; no barrier behind.
    float* mo = m_out + (size_t)b * K * HW + pwb;
#pragma unroll
    for (int s = 0; s < 2; ++s)
#pragma unroll
        for (int ni = 0; ni < 4; ++ni) {
            const int n = ni * 16 + l15;
            *(f32x4*)&mo[(size_t)n * HW + s * 16 + lg * 4] = acc[s][ni];
        }
}

// Kernel C: palette (fused) + transformed = sum_k m * palette. 4 px/thread, f32x4.
// (v7 version verbatim — best measured config.)
__global__ __launch_bounds__(256) void colorcnn_reconstruct(
    const float* __restrict__ m, const float* __restrict__ den_ws,
    const float* __restrict__ num_ws, float* __restrict__ pal_out,
    float* __restrict__ t_out)
{
    __shared__ float pl[192];
    const int b    = blockIdx.x / 49;
    const int tile = blockIdx.x % 49;
    const int t    = threadIdx.x;

    if (t < 192) {
        const int c = t >> 6, k = t & 63;
        const float v = num_ws[(b * 3 + c) * K + k] / (den_ws[b * K + k] + 1e-8f);
        pl[t] = v;
        if (tile == 0) pal_out[b * 3 * K + t] = v;
    }
    __syncthreads();

    const int p = tile * 1024 + t * 4;
    const float* mp = m + (size_t)b * K * HW + p;
    f32x4 ar = {0.f, 0.f, 0.f, 0.f}, ag = ar, ab = ar;
#pragma unroll
    for (int k = 0; k < K; ++k) {
        const f32x4 mv = *(const f32x4*)&mp[(size_t)k * HW];
        const float pr = pl[k], pg = pl[K + k], pu = pl[2 * K + k];
#pragma unroll
        for (int j = 0; j < 4; ++j) {
            ar[j] = fmaf(mv[j], pr, ar[j]);
            ag[j] = fmaf(mv[j], pg, ag[j]);
            ab[j] = fmaf(mv[j], pu, ab[j]);
        }
    }
    float* to = t_out + (size_t)b * 3 * HW + p;
    *(f32x4*)&to[0]      = ar;
    *(f32x4*)&to[HW]     = ag;
    *(f32x4*)&to[2 * HW] = ab;
}

extern "C" void kernel_launch(void* const* d_in, const int* in_sizes, int n_in,
                              void* d_out, int out_size, void* d_ws, size_t ws_size,
                              hipStream_t stream) {
    const float* img = (const float*)d_in[0];
    const float* W1  = (const float*)d_in[1];
    const float* b1  = (const float*)d_in[2];
    const float* W2  = (const float*)d_in[3];

    float* out   = (float*)d_out;
    float* t_out = out + OUT_T_OFF;
    float* m_out = out + OUT_M_OFF;
    float* p_out = out + OUT_P_OFF;

    float*  wsf    = (float*)d_ws;
    float*  den_ws = wsf + WS_DEN;
    float*  num_ws = wsf + WS_NUM;
    float4* w1p    = (float4*)(wsf + WS_W1P);
    int4*   w2b4   = (int4*)(wsf + WS_W2B);

    colorcnn_prep<<<8, 256, 0, stream>>>(W1, b1, W2, wsf, w1p, w2b4);
    colorcnn_mlp_softmax<<<dim3(HW / 256, BATCH), 512, 0, stream>>>(img, (const int4*)w1p, w2b4, m_out, den_ws, num_ws);
    colorcnn_reconstruct<<<BATCH * 49, 256, 0, stream>>>(m_out, den_ws, num_ws, p_out, t_out);
}

// Round 15
// 126.631 us; speedup vs baseline: 1.6741x; 1.3944x over previous
//
#include <hip/hip_runtime.h>
#include <hip/hip_bf16.h>

#define BATCH 16
#define HW 50176          // 224*224
#define HID 256
#define K 64

// output layout (floats): transformed [0, 2408448) | m [2408448, 53788672) | palette [53788672, +3072)
#define OUT_T_OFF 0
#define OUT_M_OFF 2408448
#define OUT_P_OFF 53788672

// workspace layout (floats): den [0,1024) | num [1024,4096) | w1p float4 [4096,5120) |
// w2b chunk-swizzled bf16 units (2048 int4 = 32KB) @ float-offset 5120
#define WS_DEN 0
#define WS_NUM 1024
#define WS_W1P 4096
#define WS_W2B 5120

typedef short bf16x8 __attribute__((ext_vector_type(8)));
typedef float f32x4  __attribute__((ext_vector_type(4)));

static __device__ __forceinline__ ushort f2bf(float x) {
    union { __hip_bfloat16 h; ushort s; } u;
    u.h = __float2bfloat16(x);
    return u.s;
}

// Prep (8 blocks): block 0 zeroes den/num + packs W1+b1 (linear float4).
// All blocks: write W2 as chunk-swizzled bf16 16B-units.
// Chunk ch (64 hid), row n, sub-unit jj=(cl*4+lg): value = W2[n][ch*64+cl*32+lg*8 .. +7],
// stored at int4 index ch*512 + n*8 + (jj ^ (n&7)).
__global__ __launch_bounds__(256) void colorcnn_prep(
    const float* __restrict__ W1, const float* __restrict__ b1,
    const float* __restrict__ W2, float* __restrict__ wsf,
    float4* __restrict__ w1p, int4* __restrict__ w2b4)
{
    const int t = threadIdx.x;
    if (blockIdx.x == 0) {
#pragma unroll
        for (int q = 0; q < 16; ++q) wsf[q * 256 + t] = 0.f;   // den[1024] + num[3072]
        w1p[t] = make_float4(W1[3 * t], W1[3 * t + 1], W1[3 * t + 2], b1[t]);
    }
    const int g  = blockIdx.x * 256 + t;    // 0..2047
    const int ch = g >> 9;
    const int n  = (g >> 3) & 63;
    const int jj = g & 7;
    const int cl = jj >> 2;
    const int lg = jj & 3;
    const int hid0 = ch * 64 + cl * 32 + lg * 8;
    union { int4 v; ushort u[8]; } un;
#pragma unroll
    for (int e = 0; e < 8; ++e) un.u[e] = f2bf(W2[n * HID + hid0 + e]);
    w2b4[ch * 512 + n * 8 + (jj ^ (n & 7))] = un.v;
}

// Kernel A: MLP via MFMA + softmax + fused den/num reduction + m store last.
// v10 body (256 thr, 4 waves x 32 px, VGPR 52 measured) + W2 streamed in 4 quarter-chunks
// (8KB) double-buffered. LDS 24KB -> 6 blocks/CU = 24 waves/CU (vs 16 before).
// launch_bounds(256,6): VGPR cap ~85, well above the ~60 needed -> no spill.
__global__ __launch_bounds__(256, 6) void colorcnn_mlp_softmax(
    const float* __restrict__ img, const int4* __restrict__ w1p4,
    const int4* __restrict__ w2b4, float* __restrict__ m_out,
    float* __restrict__ den_ws, float* __restrict__ num_ws)
{
    __shared__ int4  wbuf[2][512];   // 16 KB: double-buffered W2 quarter-chunks
    __shared__ int4  w1l[256];       // 4 KB: w1p XOR-swizzled
    __shared__ float sred[4][256];   // 4 KB: per-wave den/num partials

    const int t = threadIdx.x;
    // prologue: stage chunk 0 (512 units, 2/thread) + w1p
    wbuf[0][t]       = w2b4[t];
    wbuf[0][256 + t] = w2b4[256 + t];
    w1l[t ^ ((t >> 3) & 3)] = w1p4[t];
    __syncthreads();

    const int b    = blockIdx.y;
    const int pb   = blockIdx.x * 128;
    const int w    = t >> 6;
    const int lane = t & 63;
    const int l15  = lane & 15;
    const int lg   = lane >> 4;
    const int pwb  = pb + w * 32;
    const int x7   = l15 & 7;

    const float* ip = img + (size_t)b * 3 * HW;

    float rr[2], gg[2], uu[2];
#pragma unroll
    for (int s = 0; s < 2; ++s) {
        const int px = pwb + s * 16 + l15;
        rr[s] = ip[px]; gg[s] = ip[HW + px]; uu[s] = ip[2 * HW + px];
    }

    f32x4 acc[2][4];
#pragma unroll
    for (int s = 0; s < 2; ++s)
#pragma unroll
        for (int ni = 0; ni < 4; ++ni)
            acc[s][ni] = (f32x4){0.f, 0.f, 0.f, 0.f};

#pragma unroll
    for (int ch = 0; ch < 4; ++ch) {
        int4 stg0, stg1;
        if (ch < 3) {                                   // L2-hit prefetch, hides under MFMA
            stg0 = w2b4[(ch + 1) * 512 + t];
            stg1 = w2b4[(ch + 1) * 512 + 256 + t];
        }
#pragma unroll
        for (int cl = 0; cl < 2; ++cl) {
            const int c = ch * 2 + cl;
            union { bf16x8 v; unsigned int u[4]; } ua0, ua1;
#pragma unroll
            for (int p = 0; p < 4; ++p) {          // j = 2p, 2p+1 ; hid = c*32 + lg*8 + j
                const int hid0 = c * 32 + lg * 8 + 2 * p;
                const float4 wv0 = *(const float4*)&w1l[hid0 ^ lg];
                const float4 wv1 = *(const float4*)&w1l[(hid0 + 1) ^ lg];
                const float e0 = fmaxf(fmaf(rr[0], wv0.x, fmaf(gg[0], wv0.y, fmaf(uu[0], wv0.z, wv0.w))), 0.f);
                const float o0 = fmaxf(fmaf(rr[0], wv1.x, fmaf(gg[0], wv1.y, fmaf(uu[0], wv1.z, wv1.w))), 0.f);
                const float e1 = fmaxf(fmaf(rr[1], wv0.x, fmaf(gg[1], wv0.y, fmaf(uu[1], wv0.z, wv0.w))), 0.f);
                const float o1 = fmaxf(fmaf(rr[1], wv1.x, fmaf(gg[1], wv1.y, fmaf(uu[1], wv1.z, wv1.w))), 0.f);
                __hip_bfloat162 c0 = __float22bfloat162_rn(float2{e0, o0});
                __hip_bfloat162 c1 = __float22bfloat162_rn(float2{e1, o1});
                ua0.u[p] = *(unsigned int*)&c0;
                ua1.u[p] = *(unsigned int*)&c1;
            }
            const int sw = (cl * 4 + lg) ^ x7;
#pragma unroll
            for (int ni = 0; ni < 4; ++ni) {
                const bf16x8 bf = *(const bf16x8*)&wbuf[ch & 1][(ni * 16 + l15) * 8 + sw];
                acc[0][ni] = __builtin_amdgcn_mfma_f32_16x16x32_bf16(ua0.v, bf, acc[0][ni], 0, 0, 0);
                acc[1][ni] = __builtin_amdgcn_mfma_f32_16x16x32_bf16(ua1.v, bf, acc[1][ni], 0, 0, 0);
            }
        }
        if (ch < 3) {
            // all waves passed the iter-(ch-1) barrier, so nobody still reads wbuf[(ch+1)&1]
            wbuf[(ch + 1) & 1][t]       = stg0;
            wbuf[(ch + 1) & 1][256 + t] = stg1;
            __syncthreads();
        }
    }

    // Softmax over n=64 per pixel (no max-subtract; logits bounded, fp32 exp safe).
#pragma unroll
    for (int s = 0; s < 2; ++s) {
#pragma unroll
        for (int reg = 0; reg < 4; ++reg) {
            const float v0 = __expf(acc[s][0][reg]);
            const float v1 = __expf(acc[s][1][reg]);
            const float v2 = __expf(acc[s][2][reg]);
            const float v3 = __expf(acc[s][3][reg]);
            float sm = (v0 + v1) + (v2 + v3);
            sm += __shfl_xor(sm, 1);
            sm += __shfl_xor(sm, 2);
            sm += __shfl_xor(sm, 4);
            sm += __shfl_xor(sm, 8);
            const float inv = __builtin_amdgcn_rcpf(sm);
            acc[s][0][reg] = v0 * inv; acc[s][1][reg] = v1 * inv;
            acc[s][2][reg] = v2 * inv; acc[s][3][reg] = v3 * inv;
        }
    }

    // ---- Fused den/num reduction (before global stores; barrier stays cheap) ----
    float red[16];   // [q*4+ni], q: 0=den 1=numR 2=numG 3=numB ; n = ni*16 + l15
#pragma unroll
    for (int i = 0; i < 16; ++i) red[i] = 0.f;
#pragma unroll
    for (int s = 0; s < 2; ++s) {
        const int pxb = pwb + s * 16 + lg * 4;
        const f32x4 rC = *(const f32x4*)&ip[pxb];
        const f32x4 gC = *(const f32x4*)&ip[HW + pxb];
        const f32x4 uC = *(const f32x4*)&ip[2 * HW + pxb];
#pragma unroll
        for (int ni = 0; ni < 4; ++ni) {
#pragma unroll
            for (int reg = 0; reg < 4; ++reg) {
                const float mv = acc[s][ni][reg];
                red[ni]      += mv;
                red[4 + ni]   = fmaf(rC[reg], mv, red[4 + ni]);
                red[8 + ni]   = fmaf(gC[reg], mv, red[8 + ni]);
                red[12 + ni]  = fmaf(uC[reg], mv, red[12 + ni]);
            }
        }
    }
#pragma unroll
    for (int i = 0; i < 16; ++i) {
        red[i] += __shfl_xor(red[i], 16);
        red[i] += __shfl_xor(red[i], 32);
    }
    if (lg == 0) {
#pragma unroll
        for (int ni = 0; ni < 4; ++ni) {
            const int n = ni * 16 + l15;
            sred[w][n]       = red[ni];
            sred[w][64 + n]  = red[4 + ni];
            sred[w][128 + n] = red[8 + ni];
            sred[w][192 + n] = red[12 + ni];
        }
    }
    __syncthreads();
    {
        const int q = t >> 6, n = t & 63;
        const float v = sred[0][t] + sred[1][t] + sred[2][t] + sred[3][t];
        if (q == 0) atomicAdd(&den_ws[b * K + n], v);
        else        atomicAdd(&num_ws[(b * 3 + (q - 1)) * K + n], v);
    }

    // Store m LAST: per (s,ni) the 4 regs are 4 consecutive px -> dwordx4; no barrier behind.
    float* mo = m_out + (size_t)b * K * HW + pwb;
#pragma unroll
    for (int s = 0; s < 2; ++s)
#pragma unroll
        for (int ni = 0; ni < 4; ++ni) {
            const int n = ni * 16 + l15;
            *(f32x4*)&mo[(size_t)n * HW + s * 16 + lg * 4] = acc[s][ni];
        }
}

// Kernel C: palette (fused) + transformed = sum_k m * palette. 4 px/thread, f32x4.
// (v7 version verbatim — best measured config.)
__global__ __launch_bounds__(256) void colorcnn_reconstruct(
    const float* __restrict__ m, const float* __restrict__ den_ws,
    const float* __restrict__ num_ws, float* __restrict__ pal_out,
    float* __restrict__ t_out)
{
    __shared__ float pl[192];
    const int b    = blockIdx.x / 49;
    const int tile = blockIdx.x % 49;
    const int t    = threadIdx.x;

    if (t < 192) {
        const int c = t >> 6, k = t & 63;
        const float v = num_ws[(b * 3 + c) * K + k] / (den_ws[b * K + k] + 1e-8f);
        pl[t] = v;
        if (tile == 0) pal_out[b * 3 * K + t] = v;
    }
    __syncthreads();

    const int p = tile * 1024 + t * 4;
    const float* mp = m + (size_t)b * K * HW + p;
    f32x4 ar = {0.f, 0.f, 0.f, 0.f}, ag = ar, ab = ar;
#pragma unroll
    for (int k = 0; k < K; ++k) {
        const f32x4 mv = *(const f32x4*)&mp[(size_t)k * HW];
        const float pr = pl[k], pg = pl[K + k], pu = pl[2 * K + k];
#pragma unroll
        for (int j = 0; j < 4; ++j) {
            ar[j] = fmaf(mv[j], pr, ar[j]);
            ag[j] = fmaf(mv[j], pg, ag[j]);
            ab[j] = fmaf(mv[j], pu, ab[j]);
        }
    }
    float* to = t_out + (size_t)b * 3 * HW + p;
    *(f32x4*)&to[0]      = ar;
    *(f32x4*)&to[HW]     = ag;
    *(f32x4*)&to[2 * HW] = ab;
}

extern "C" void kernel_launch(void* const* d_in, const int* in_sizes, int n_in,
                              void* d_out, int out_size, void* d_ws, size_t ws_size,
                              hipStream_t stream) {
    const float* img = (const float*)d_in[0];
    const float* W1  = (const float*)d_in[1];
    const float* b1  = (const float*)d_in[2];
    const float* W2  = (const float*)d_in[3];

    float* out   = (float*)d_out;
    float* t_out = out + OUT_T_OFF;
    float* m_out = out + OUT_M_OFF;
    float* p_out = out + OUT_P_OFF;

    float*  wsf    = (float*)d_ws;
    float*  den_ws = wsf + WS_DEN;
    float*  num_ws = wsf + WS_NUM;
    float4* w1p    = (float4*)(wsf + WS_W1P);
    int4*   w2b4   = (int4*)(wsf + WS_W2B);

    colorcnn_prep<<<8, 256, 0, stream>>>(W1, b1, W2, wsf, w1p, w2b4);
    colorcnn_mlp_softmax<<<dim3(HW / 128, BATCH), 256, 0, stream>>>(img, (const int4*)w1p, w2b4, m_out, den_ws, num_ws);
    colorcnn_reconstruct<<<BATCH * 49, 256, 0, stream>>>(m_out, den_ws, num_ws, p_out, t_out);
}

// Round 16
// 124.976 us; speedup vs baseline: 1.6962x; 1.0132x over previous
//
#include <hip/hip_runtime.h>
#include <hip/hip_bf16.h>

#define BATCH 16
#define HW 50176          // 224*224
#define HID 256
#define K 64

// output layout (floats): transformed [0, 2408448) | m [2408448, 53788672) | palette [53788672, +3072)
#define OUT_T_OFF 0
#define OUT_M_OFF 2408448
#define OUT_P_OFF 53788672

// workspace layout (floats): den [0,1024) | num [1024,4096) | w1pp pair-packed float4 [4096,5120) |
// w2b bf16 @ float-offset 5120 (32KB)
#define WS_DEN 0
#define WS_NUM 1024
#define WS_W1P 4096
#define WS_W2B 5120

typedef short bf16x8 __attribute__((ext_vector_type(8)));
typedef float f32x4  __attribute__((ext_vector_type(4)));
typedef float f32x2  __attribute__((ext_vector_type(2)));

static __device__ __forceinline__ ushort f2bf(float x) {
    union { __hip_bfloat16 h; ushort s; } u;
    u.h = __float2bfloat16(x);
    return u.s;
}

// Prep (8 blocks): block 0 zeroes den/num + packs W1+b1 as hid-PAIRS (SoA within pair):
//   pair q: unitA = {W1[2q][0], W1[2q+1][0], W1[2q][1], W1[2q+1][1]}
//           unitB = {W1[2q][2], W1[2q+1][2], b1[2q],   b1[2q+1]}
// All blocks convert W2 to bf16 (linear; A swizzles while staging).
__global__ __launch_bounds__(256) void colorcnn_prep(
    const float* __restrict__ W1, const float* __restrict__ b1,
    const float* __restrict__ W2, float* __restrict__ wsf,
    float4* __restrict__ w1pp, ushort* __restrict__ w2b)
{
    const int t = threadIdx.x;
    if (blockIdx.x == 0) {
#pragma unroll
        for (int q = 0; q < 16; ++q) wsf[q * 256 + t] = 0.f;   // den[1024] + num[3072]
        const int q = t >> 1;
        if ((t & 1) == 0)
            w1pp[t] = make_float4(W1[6 * q + 0], W1[6 * q + 3], W1[6 * q + 1], W1[6 * q + 4]);
        else
            w1pp[t] = make_float4(W1[6 * q + 2], W1[6 * q + 5], b1[2 * q], b1[2 * q + 1]);
    }
#pragma unroll
    for (int q = 0; q < 8; ++q) {
        const int i = (blockIdx.x * 8 + q) * 256 + t;
        w2b[i] = f2bf(W2[i]);
    }
}

// Kernel A: MLP via MFMA + softmax + fused den/num reduction + m store last.
// v10 skeleton (256 thr, 4 waves x 32 px, no in-loop barriers) with:
//  - w1 pair-packed LINEAR in LDS: all 64 reads are base(lg*128)+imm-offset (zero addr VALU)
//  - packed f32x2 h-build (v_pk_fma_f32 / v_pk_max_f32)
__global__ __launch_bounds__(256, 4) void colorcnn_mlp_softmax(
    const float* __restrict__ img, const int4* __restrict__ w1pp4,
    const ushort* __restrict__ w2b, float* __restrict__ m_out,
    float* __restrict__ den_ws, float* __restrict__ num_ws)
{
    __shared__ int4 lds[2304];       // [0,2048): w2b swizzled; [2048,2304): w1pp LINEAR
    __shared__ float sred[4][256];   // per-wave den/num partials

    const int t = threadIdx.x;
    const int4* w2b16 = (const int4*)w2b;
#pragma unroll
    for (int q = 0; q < 8; ++q) {
        const int i = t + q * 256;
        const int n = i >> 5, s = i & 31;
        lds[n * 32 + (s ^ (n & 7))] = w2b16[i];
    }
    lds[2048 + t] = w1pp4[t];        // linear pair-packed
    __syncthreads();

    const int b    = blockIdx.y;
    const int pb   = blockIdx.x * 128;
    const int w    = t >> 6;
    const int lane = t & 63;
    const int l15  = lane & 15;
    const int lg   = lane >> 4;
    const int pwb  = pb + w * 32;
    const int x7   = l15 & 7;

    const float* ip = img + (size_t)b * 3 * HW;

    float rr[2], gg[2], uu[2];
#pragma unroll
    for (int s = 0; s < 2; ++s) {
        const int px = pwb + s * 16 + l15;
        rr[s] = ip[px]; gg[s] = ip[HW + px]; uu[s] = ip[2 * HW + px];
    }

    f32x4 acc[2][4];
#pragma unroll
    for (int s = 0; s < 2; ++s)
#pragma unroll
        for (int ni = 0; ni < 4; ++ni)
            acc[s][ni] = (f32x4){0.f, 0.f, 0.f, 0.f};

    // lane base into the w1pp region: pair index pr = c*16 + lg*4 + p; unit = 2048 + pr*2 + q
    // -> byte = (2048 + lg*8)*16 + (c*512 + p*32 + q*16)  [imm]
    const float4* w1base = (const float4*)&lds[2048 + lg * 8];

#pragma unroll
    for (int c = 0; c < 8; ++c) {
        union { bf16x8 v; unsigned int u[4]; } ua0, ua1;
#pragma unroll
        for (int p = 0; p < 4; ++p) {          // hid pair = c*16 + lg*4 + p  (hids 2pr, 2pr+1)
            const float4 uA = w1base[c * 32 + p * 2];       // {w0a,w0b,w1a,w1b}
            const float4 uB = w1base[c * 32 + p * 2 + 1];   // {w2a,w2b,ba,bb}
            const f32x2 wA0 = {uA.x, uA.y};
            const f32x2 wA1 = {uA.z, uA.w};
            const f32x2 wB0 = {uB.x, uB.y};
            const f32x2 bb2 = {uB.z, uB.w};
            const f32x2 z2  = {0.f, 0.f};

            f32x2 h0 = bb2, h1 = bb2;
            {
                const f32x2 r0 = {rr[0], rr[0]}, g0 = {gg[0], gg[0]}, u0 = {uu[0], uu[0]};
                h0 = r0 * wA0 + h0; h0 = g0 * wA1 + h0; h0 = u0 * wB0 + h0;
                h0 = __builtin_elementwise_max(h0, z2);
            }
            {
                const f32x2 r1 = {rr[1], rr[1]}, g1 = {gg[1], gg[1]}, u1 = {uu[1], uu[1]};
                h1 = r1 * wA0 + h1; h1 = g1 * wA1 + h1; h1 = u1 * wB0 + h1;
                h1 = __builtin_elementwise_max(h1, z2);
            }
            __hip_bfloat162 c0 = __float22bfloat162_rn(float2{h0.x, h0.y});
            __hip_bfloat162 c1 = __float22bfloat162_rn(float2{h1.x, h1.y});
            ua0.u[p] = *(unsigned int*)&c0;
            ua1.u[p] = *(unsigned int*)&c1;
        }
        const int sw = (c * 4 + lg) ^ x7;
#pragma unroll
        for (int ni = 0; ni < 4; ++ni) {
            const bf16x8 bf = *(const bf16x8*)&lds[(ni * 16 + l15) * 32 + sw];
            acc[0][ni] = __builtin_amdgcn_mfma_f32_16x16x32_bf16(ua0.v, bf, acc[0][ni], 0, 0, 0);
            acc[1][ni] = __builtin_amdgcn_mfma_f32_16x16x32_bf16(ua1.v, bf, acc[1][ni], 0, 0, 0);
        }
    }

    // Softmax over n=64 per pixel (no max-subtract; logits bounded, fp32 exp safe).
#pragma unroll
    for (int s = 0; s < 2; ++s) {
#pragma unroll
        for (int reg = 0; reg < 4; ++reg) {
            const float v0 = __expf(acc[s][0][reg]);
            const float v1 = __expf(acc[s][1][reg]);
            const float v2 = __expf(acc[s][2][reg]);
            const float v3 = __expf(acc[s][3][reg]);
            float sm = (v0 + v1) + (v2 + v3);
            sm += __shfl_xor(sm, 1);
            sm += __shfl_xor(sm, 2);
            sm += __shfl_xor(sm, 4);
            sm += __shfl_xor(sm, 8);
            const float inv = __builtin_amdgcn_rcpf(sm);
            acc[s][0][reg] = v0 * inv; acc[s][1][reg] = v1 * inv;
            acc[s][2][reg] = v2 * inv; acc[s][3][reg] = v3 * inv;
        }
    }

    // ---- Fused den/num reduction (before global stores; barrier stays cheap) ----
    float red[16];   // [q*4+ni], q: 0=den 1=numR 2=numG 3=numB ; n = ni*16 + l15
#pragma unroll
    for (int i = 0; i < 16; ++i) red[i] = 0.f;
#pragma unroll
    for (int s = 0; s < 2; ++s) {
        const int pxb = pwb + s * 16 + lg * 4;
        const f32x4 rC = *(const f32x4*)&ip[pxb];
        const f32x4 gC = *(const f32x4*)&ip[HW + pxb];
        const f32x4 uC = *(const f32x4*)&ip[2 * HW + pxb];
#pragma unroll
        for (int ni = 0; ni < 4; ++ni) {
#pragma unroll
            for (int reg = 0; reg < 4; ++reg) {
                const float mv = acc[s][ni][reg];
                red[ni]      += mv;
                red[4 + ni]   = fmaf(rC[reg], mv, red[4 + ni]);
                red[8 + ni]   = fmaf(gC[reg], mv, red[8 + ni]);
                red[12 + ni]  = fmaf(uC[reg], mv, red[12 + ni]);
            }
        }
    }
#pragma unroll
    for (int i = 0; i < 16; ++i) {
        red[i] += __shfl_xor(red[i], 16);
        red[i] += __shfl_xor(red[i], 32);
    }
    if (lg == 0) {
#pragma unroll
        for (int ni = 0; ni < 4; ++ni) {
            const int n = ni * 16 + l15;
            sred[w][n]       = red[ni];
            sred[w][64 + n]  = red[4 + ni];
            sred[w][128 + n] = red[8 + ni];
            sred[w][192 + n] = red[12 + ni];
        }
    }
    __syncthreads();
    {
        const int q = t >> 6, n = t & 63;
        const float v = sred[0][t] + sred[1][t] + sred[2][t] + sred[3][t];
        if (q == 0) atomicAdd(&den_ws[b * K + n], v);
        else        atomicAdd(&num_ws[(b * 3 + (q - 1)) * K + n], v);
    }

    // Store m LAST: per (s,ni) the 4 regs are 4 consecutive px -> dwordx4; no barrier behind.
    float* mo = m_out + (size_t)b * K * HW + pwb;
#pragma unroll
    for (int s = 0; s < 2; ++s)
#pragma unroll
        for (int ni = 0; ni < 4; ++ni) {
            const int n = ni * 16 + l15;
            *(f32x4*)&mo[(size_t)n * HW + s * 16 + lg * 4] = acc[s][ni];
        }
}

// Kernel C: palette (fused) + transformed = sum_k m * palette. 4 px/thread, f32x4.
// (v7 version verbatim — best measured config.)
__global__ __launch_bounds__(256) void colorcnn_reconstruct(
    const float* __restrict__ m, const float* __restrict__ den_ws,
    const float* __restrict__ num_ws, float* __restrict__ pal_out,
    float* __restrict__ t_out)
{
    __shared__ float pl[192];
    const int b    = blockIdx.x / 49;
    const int tile = blockIdx.x % 49;
    const int t    = threadIdx.x;

    if (t < 192) {
        const int c = t >> 6, k = t & 63;
        const float v = num_ws[(b * 3 + c) * K + k] / (den_ws[b * K + k] + 1e-8f);
        pl[t] = v;
        if (tile == 0) pal_out[b * 3 * K + t] = v;
    }
    __syncthreads();

    const int p = tile * 1024 + t * 4;
    const float* mp = m + (size_t)b * K * HW + p;
    f32x4 ar = {0.f, 0.f, 0.f, 0.f}, ag = ar, ab = ar;
#pragma unroll
    for (int k = 0; k < K; ++k) {
        const f32x4 mv = *(const f32x4*)&mp[(size_t)k * HW];
        const float pr = pl[k], pg = pl[K + k], pu = pl[2 * K + k];
#pragma unroll
        for (int j = 0; j < 4; ++j) {
            ar[j] = fmaf(mv[j], pr, ar[j]);
            ag[j] = fmaf(mv[j], pg, ag[j]);
            ab[j] = fmaf(mv[j], pu, ab[j]);
        }
    }
    float* to = t_out + (size_t)b * 3 * HW + p;
    *(f32x4*)&to[0]      = ar;
    *(f32x4*)&to[HW]     = ag;
    *(f32x4*)&to[2 * HW] = ab;
}

extern "C" void kernel_launch(void* const* d_in, const int* in_sizes, int n_in,
                              void* d_out, int out_size, void* d_ws, size_t ws_size,
                              hipStream_t stream) {
    const float* img = (const float*)d_in[0];
    const float* W1  = (const float*)d_in[1];
    const float* b1  = (const float*)d_in[2];
    const float* W2  = (const float*)d_in[3];

    float* out   = (float*)d_out;
    float* t_out = out + OUT_T_OFF;
    float* m_out = out + OUT_M_OFF;
    float* p_out = out + OUT_P_OFF;

    float*  wsf    = (float*)d_ws;
    float*  den_ws = wsf + WS_DEN;
    float*  num_ws = wsf + WS_NUM;
    float4* w1pp   = (float4*)(wsf + WS_W1P);
    ushort* w2b    = (ushort*)(wsf + WS_W2B);

    colorcnn_prep<<<8, 256, 0, stream>>>(W1, b1, W2, wsf, w1pp, w2b);
    colorcnn_mlp_softmax<<<dim3(HW / 128, BATCH), 256, 0, stream>>>(img, (const int4*)w1pp, w2b, m_out, den_ws, num_ws);
    colorcnn_reconstruct<<<BATCH * 49, 256, 0, stream>>>(m_out, den_ws, num_ws, p_out, t_out);
}

// Round 17
// 124.494 us; speedup vs baseline: 1.7028x; 1.0039x over previous
//
#include <hip/hip_runtime.h>
#include <hip/hip_bf16.h>

#define BATCH 16
#define HW 50176          // 224*224
#define HID 256
#define K 64

// output layout (floats): transformed [0, 2408448) | m [2408448, 53788672) | palette [53788672, +3072)
#define OUT_T_OFF 0
#define OUT_M_OFF 2408448
#define OUT_P_OFF 53788672

// workspace layout (floats): den [0,1024) | num [1024,4096) | w1pp pair-packed float4 [4096,5120) |
// w2b bf16 @ float-offset 5120 (32KB)
#define WS_DEN 0
#define WS_NUM 1024
#define WS_W1P 4096
#define WS_W2B 5120

typedef short bf16x8 __attribute__((ext_vector_type(8)));
typedef float f32x4  __attribute__((ext_vector_type(4)));
typedef float f32x2  __attribute__((ext_vector_type(2)));

static __device__ __forceinline__ ushort f2bf(float x) {
    union { __hip_bfloat16 h; ushort s; } u;
    u.h = __float2bfloat16(x);
    return u.s;
}

// Prep (8 blocks): block 0 zeroes den/num + packs W1+b1 as hid-PAIRS (SoA within pair):
//   pair q: unitA = {W1[2q][0], W1[2q+1][0], W1[2q][1], W1[2q+1][1]}
//           unitB = {W1[2q][2], W1[2q+1][2], b1[2q],   b1[2q+1]}
// All blocks convert W2 to bf16 (linear; A swizzles while staging).
__global__ __launch_bounds__(256) void colorcnn_prep(
    const float* __restrict__ W1, const float* __restrict__ b1,
    const float* __restrict__ W2, float* __restrict__ wsf,
    float4* __restrict__ w1pp, ushort* __restrict__ w2b)
{
    const int t = threadIdx.x;
    if (blockIdx.x == 0) {
#pragma unroll
        for (int q = 0; q < 16; ++q) wsf[q * 256 + t] = 0.f;   // den[1024] + num[3072]
        const int q = t >> 1;
        if ((t & 1) == 0)
            w1pp[t] = make_float4(W1[6 * q + 0], W1[6 * q + 3], W1[6 * q + 1], W1[6 * q + 4]);
        else
            w1pp[t] = make_float4(W1[6 * q + 2], W1[6 * q + 5], b1[2 * q], b1[2 * q + 1]);
    }
#pragma unroll
    for (int q = 0; q < 8; ++q) {
        const int i = (blockIdx.x * 8 + q) * 256 + t;
        w2b[i] = f2bf(W2[i]);
    }
}

// Kernel A: MLP via MFMA + softmax + fused den/num reduction + LDS-transposed m store.
// Store path: stage the 128px x 64k tile in LDS (reusing the dead w2b region), then each
// wave writes 16 rows as ONE 512B-contiguous dwordx2 instruction per row (vs 16x64B scatter).
__global__ __launch_bounds__(256, 4) void colorcnn_mlp_softmax(
    const float* __restrict__ img, const int4* __restrict__ w1pp4,
    const ushort* __restrict__ w2b, float* __restrict__ m_out,
    float* __restrict__ den_ws, float* __restrict__ num_ws)
{
    __shared__ int4 lds[2304];       // [0,2048): w2b swizzled, later reused as m-tile; [2048,2304): w1pp
    __shared__ float sred[4][256];   // per-wave den/num partials

    const int t = threadIdx.x;
    const int4* w2b16 = (const int4*)w2b;
#pragma unroll
    for (int q = 0; q < 8; ++q) {
        const int i = t + q * 256;
        const int n = i >> 5, s = i & 31;
        lds[n * 32 + (s ^ (n & 7))] = w2b16[i];
    }
    lds[2048 + t] = w1pp4[t];        // linear pair-packed
    __syncthreads();

    const int b    = blockIdx.y;
    const int pb   = blockIdx.x * 128;
    const int w    = t >> 6;
    const int lane = t & 63;
    const int l15  = lane & 15;
    const int lg   = lane >> 4;
    const int pwb  = pb + w * 32;
    const int x7   = l15 & 7;

    const float* ip = img + (size_t)b * 3 * HW;

    float rr[2], gg[2], uu[2];
#pragma unroll
    for (int s = 0; s < 2; ++s) {
        const int px = pwb + s * 16 + l15;
        rr[s] = ip[px]; gg[s] = ip[HW + px]; uu[s] = ip[2 * HW + px];
    }

    f32x4 acc[2][4];
#pragma unroll
    for (int s = 0; s < 2; ++s)
#pragma unroll
        for (int ni = 0; ni < 4; ++ni)
            acc[s][ni] = (f32x4){0.f, 0.f, 0.f, 0.f};

    const float4* w1base = (const float4*)&lds[2048 + lg * 8];

#pragma unroll
    for (int c = 0; c < 8; ++c) {
        union { bf16x8 v; unsigned int u[4]; } ua0, ua1;
#pragma unroll
        for (int p = 0; p < 4; ++p) {          // hid pair = c*16 + lg*4 + p
            const float4 uA = w1base[c * 32 + p * 2];       // {w0a,w0b,w1a,w1b}
            const float4 uB = w1base[c * 32 + p * 2 + 1];   // {w2a,w2b,ba,bb}
            const f32x2 wA0 = {uA.x, uA.y};
            const f32x2 wA1 = {uA.z, uA.w};
            const f32x2 wB0 = {uB.x, uB.y};
            const f32x2 bb2 = {uB.z, uB.w};
            const f32x2 z2  = {0.f, 0.f};

            f32x2 h0 = bb2, h1 = bb2;
            {
                const f32x2 r0 = {rr[0], rr[0]}, g0 = {gg[0], gg[0]}, u0 = {uu[0], uu[0]};
                h0 = r0 * wA0 + h0; h0 = g0 * wA1 + h0; h0 = u0 * wB0 + h0;
                h0 = __builtin_elementwise_max(h0, z2);
            }
            {
                const f32x2 r1 = {rr[1], rr[1]}, g1 = {gg[1], gg[1]}, u1 = {uu[1], uu[1]};
                h1 = r1 * wA0 + h1; h1 = g1 * wA1 + h1; h1 = u1 * wB0 + h1;
                h1 = __builtin_elementwise_max(h1, z2);
            }
            __hip_bfloat162 c0 = __float22bfloat162_rn(float2{h0.x, h0.y});
            __hip_bfloat162 c1 = __float22bfloat162_rn(float2{h1.x, h1.y});
            ua0.u[p] = *(unsigned int*)&c0;
            ua1.u[p] = *(unsigned int*)&c1;
        }
        const int sw = (c * 4 + lg) ^ x7;
#pragma unroll
        for (int ni = 0; ni < 4; ++ni) {
            const bf16x8 bf = *(const bf16x8*)&lds[(ni * 16 + l15) * 32 + sw];
            acc[0][ni] = __builtin_amdgcn_mfma_f32_16x16x32_bf16(ua0.v, bf, acc[0][ni], 0, 0, 0);
            acc[1][ni] = __builtin_amdgcn_mfma_f32_16x16x32_bf16(ua1.v, bf, acc[1][ni], 0, 0, 0);
        }
    }

    // Softmax over n=64 per pixel (no max-subtract; logits bounded, fp32 exp safe).
#pragma unroll
    for (int s = 0; s < 2; ++s) {
#pragma unroll
        for (int reg = 0; reg < 4; ++reg) {
            const float v0 = __expf(acc[s][0][reg]);
            const float v1 = __expf(acc[s][1][reg]);
            const float v2 = __expf(acc[s][2][reg]);
            const float v3 = __expf(acc[s][3][reg]);
            float sm = (v0 + v1) + (v2 + v3);
            sm += __shfl_xor(sm, 1);
            sm += __shfl_xor(sm, 2);
            sm += __shfl_xor(sm, 4);
            sm += __shfl_xor(sm, 8);
            const float inv = __builtin_amdgcn_rcpf(sm);
            acc[s][0][reg] = v0 * inv; acc[s][1][reg] = v1 * inv;
            acc[s][2][reg] = v2 * inv; acc[s][3][reg] = v3 * inv;
        }
    }

    // ---- Fused den/num reduction ----
    float red[16];   // [q*4+ni], q: 0=den 1=numR 2=numG 3=numB ; n = ni*16 + l15
#pragma unroll
    for (int i = 0; i < 16; ++i) red[i] = 0.f;
#pragma unroll
    for (int s = 0; s < 2; ++s) {
        const int pxb = pwb + s * 16 + lg * 4;
        const f32x4 rC = *(const f32x4*)&ip[pxb];
        const f32x4 gC = *(const f32x4*)&ip[HW + pxb];
        const f32x4 uC = *(const f32x4*)&ip[2 * HW + pxb];
#pragma unroll
        for (int ni = 0; ni < 4; ++ni) {
#pragma unroll
            for (int reg = 0; reg < 4; ++reg) {
                const float mv = acc[s][ni][reg];
                red[ni]      += mv;
                red[4 + ni]   = fmaf(rC[reg], mv, red[4 + ni]);
                red[8 + ni]   = fmaf(gC[reg], mv, red[8 + ni]);
                red[12 + ni]  = fmaf(uC[reg], mv, red[12 + ni]);
            }
        }
    }
#pragma unroll
    for (int i = 0; i < 16; ++i) {
        red[i] += __shfl_xor(red[i], 16);
        red[i] += __shfl_xor(red[i], 32);
    }
    if (lg == 0) {
#pragma unroll
        for (int ni = 0; ni < 4; ++ni) {
            const int n = ni * 16 + l15;
            sred[w][n]       = red[ni];
            sred[w][64 + n]  = red[4 + ni];
            sred[w][128 + n] = red[8 + ni];
            sred[w][192 + n] = red[12 + ni];
        }
    }
    __syncthreads();   // sred ready AND all MFMA reads of the w2b region complete

    {
        const int q = t >> 6, n = t & 63;
        const float v = sred[0][t] + sred[1][t] + sred[2][t] + sred[3][t];
        if (q == 0) atomicAdd(&den_ws[b * K + n], v);
        else        atomicAdd(&num_ws[(b * 3 + (q - 1)) * K + n], v);
    }

    // ---- m-tile: stage acc in LDS (reuse w2b region; row stride 132 floats = 16B-aligned,
    // structurally conflict-free), then 512B-contiguous dwordx2 row stores ----
    float* mt = (float*)&lds[0];     // 64 rows x 132 floats = 33792 B <= 36864 B
#pragma unroll
    for (int s = 0; s < 2; ++s)
#pragma unroll
        for (int ni = 0; ni < 4; ++ni) {
            const int n  = ni * 16 + l15;
            const int px = w * 32 + s * 16 + lg * 4;
            *(f32x4*)&mt[n * 132 + px] = acc[s][ni];
        }
    __syncthreads();

    // wave w stores rows 16w..16w+15; one dwordx2 instruction = 512B contiguous per row
    float* mo = m_out + (size_t)b * K * HW + pb;
#pragma unroll
    for (int r = 0; r < 16; ++r) {
        const int n = w * 16 + r;
        const f32x2 v = *(const f32x2*)&mt[n * 132 + lane * 2];
        *(f32x2*)&mo[(size_t)n * HW + lane * 2] = v;
    }
}

// Kernel C: palette (fused) + transformed = sum_k m * palette. 4 px/thread, f32x4.
// (v7 version verbatim — best measured config.)
__global__ __launch_bounds__(256) void colorcnn_reconstruct(
    const float* __restrict__ m, const float* __restrict__ den_ws,
    const float* __restrict__ num_ws, float* __restrict__ pal_out,
    float* __restrict__ t_out)
{
    __shared__ float pl[192];
    const int b    = blockIdx.x / 49;
    const int tile = blockIdx.x % 49;
    const int t    = threadIdx.x;

    if (t < 192) {
        const int c = t >> 6, k = t & 63;
        const float v = num_ws[(b * 3 + c) * K + k] / (den_ws[b * K + k] + 1e-8f);
        pl[t] = v;
        if (tile == 0) pal_out[b * 3 * K + t] = v;
    }
    __syncthreads();

    const int p = tile * 1024 + t * 4;
    const float* mp = m + (size_t)b * K * HW + p;
    f32x4 ar = {0.f, 0.f, 0.f, 0.f}, ag = ar, ab = ar;
#pragma unroll
    for (int k = 0; k < K; ++k) {
        const f32x4 mv = *(const f32x4*)&mp[(size_t)k * HW];
        const float pr = pl[k], pg = pl[K + k], pu = pl[2 * K + k];
#pragma unroll
        for (int j = 0; j < 4; ++j) {
            ar[j] = fmaf(mv[j], pr, ar[j]);
            ag[j] = fmaf(mv[j], pg, ag[j]);
            ab[j] = fmaf(mv[j], pu, ab[j]);
        }
    }
    float* to = t_out + (size_t)b * 3 * HW + p;
    *(f32x4*)&to[0]      = ar;
    *(f32x4*)&to[HW]     = ag;
    *(f32x4*)&to[2 * HW] = ab;
}

extern "C" void kernel_launch(void* const* d_in, const int* in_sizes, int n_in,
                              void* d_out, int out_size, void* d_ws, size_t ws_size,
                              hipStream_t stream) {
    const float* img = (const float*)d_in[0];
    const float* W1  = (const float*)d_in[1];
    const float* b1  = (const float*)d_in[2];
    const float* W2  = (const float*)d_in[3];

    float* out   = (float*)d_out;
    float* t_out = out + OUT_T_OFF;
    float* m_out = out + OUT_M_OFF;
    float* p_out = out + OUT_P_OFF;

    float*  wsf    = (float*)d_ws;
    float*  den_ws = wsf + WS_DEN;
    float*  num_ws = wsf + WS_NUM;
    float4* w1pp   = (float4*)(wsf + WS_W1P);
    ushort* w2b    = (ushort*)(wsf + WS_W2B);

    colorcnn_prep<<<8, 256, 0, stream>>>(W1, b1, W2, wsf, w1pp, w2b);
    colorcnn_mlp_softmax<<<dim3(HW / 128, BATCH), 256, 0, stream>>>(img, (const int4*)w1pp, w2b, m_out, den_ws, num_ws);
    colorcnn_reconstruct<<<BATCH * 49, 256, 0, stream>>>(m_out, den_ws, num_ws, p_out, t_out);
}